// Round 2
// 297.192 us; speedup vs baseline: 1.0276x; 1.0276x over previous
//
#include <hip/hip_runtime.h>

// ---------------------------------------------------------------------------
// PositionEncoder: per token (B*T = 262144), output 272 f32:
//   x[0:6] | emb[idx1] (128) | x[6:10] | emb[idx2] (128) | x[10:16]
// idx from matching (x[4],x[5]) / (x[8],x[9]) vs 26 nodes,
// close iff |p - node| <= 0.01 + 1e-5*|node| per dim; idx = first match + 1.
//
// R1..R4 history: LDS output tile + coalesced (nt) float4 stream ~125 us
//   kernel-side (dur_us 305 includes ~180 us harness fill). nt-vs-plain was
//   a wash => NOT write-allocate-bound; the 34 KB tile capped occupancy at
//   4 blocks/CU and 3 barriers drained the store pipe between phases.
// R5: no output tile. Direct register->global nt stores, one barrier.
//   Sources resolved branchlessly per 8B half from LDS: x tile (4 KB) +
//   emb rows 0..26 (13.5 KB; idx is provably in [0,26]). 18 KB LDS ->
//   8 blocks/CU, 32 waves/CU. Steady state: 2x ds_read_b64 + 1 nt dwordx4.
// R6: fix macro var shadowing compile error (BODY's `l` vs tail-loop `l`).
// ---------------------------------------------------------------------------

#define TOK 64          // tokens per block
#define THREADS 256

typedef float vfloat4 __attribute__((ext_vector_type(4)));  // native vector

constexpr float kNX[26] = {
    0.5454545454545454f, 0.6022727272727273f, 0.5454545454545454f,
    0.6022727272727273f, 0.4772727272727273f, 0.42045454545454547f,
    0.42045454545454547f, 0.4772727272727273f, 0.32954545454545453f,
    0.42045454545454547f, 0.4772727272727273f, 0.4772727272727273f,
    0.42045454545454547f, 0.32954545454545453f, 0.5727272727272728f,
    0.7613636363636364f, 0.8181818181818182f, 0.8181818181818182f,
    0.7613636363636364f, 0.7909090909090909f, 0.9431818181818182f,
    1.0f, 1.0f, 0.9431818181818182f, 0.9727272727272728f, 0.9727272727272728f};
constexpr float kNY[26] = {
    0.76f, 0.76f, 0.86f, 0.86f, 0.76f, 0.76f, 0.86f, 0.86f, 0.808f,
    0.48f, 0.48f, 0.38f, 0.38f, 0.428f, 0.62f, 0.76f, 0.76f, 0.86f,
    0.86f, 0.62f, 0.76f, 0.76f, 0.86f, 0.86f, 0.62f, 1.0f};

__device__ __forceinline__ int point_index(float px, float py) {
#pragma clang fp contract(off)
    int idx = 0;
    // Reverse iterate + overwrite => lowest-index match wins (== argmax of
    // the boolean "close" vector, matching the reference exactly).
#pragma unroll
    for (int n = 25; n >= 0; --n) {
        float tx = 0.01f + 1.0e-5f * kNX[n];   // compile-time folded
        float ty = 0.01f + 1.0e-5f * kNY[n];
        bool c = (fabsf(px - kNX[n]) <= tx) && (fabsf(py - kNY[n]) <= ty);
        if (c) idx = n + 1;
    }
    return idx;
}

__global__ __launch_bounds__(THREADS) void pos_enc_kernel(
    const float* __restrict__ x, const float* __restrict__ emb,
    float* __restrict__ out, int n_tokens) {
    __shared__ float xs[TOK * 16];      // 4 KB   staged x tile
    __shared__ float semb[27 * 128];    // 13.5 KB emb rows 0..26 (only reachable)
    __shared__ int   sidx[2 * TOK];     // 0.5 KB node indices

    const int tid  = threadIdx.x;
    const int tok0 = blockIdx.x * TOK;
    const int ntok = min(TOK, n_tokens - tok0);

    // ---- stage emb rows 0..26: 864 float4, coalesced, L2-hot after block 0
    for (int i = tid; i < 27 * 32; i += THREADS)
        ((vfloat4*)semb)[i] = ((const vfloat4*)emb)[i];

    // ---- stage x tile (64 tok * 4 float4 = 256, one per thread) and compute
    //      node indices straight from the staging registers: the thread that
    //      loads float4 #1 of token t holds (x4,x5); #2 holds (x8,x9).
    if (tid < ntok * 4) {
        vfloat4 v = ((const vfloat4*)x)[(long long)tok0 * 4 + tid];
        ((vfloat4*)xs)[tid] = v;
        int q = tid & 3, t = tid >> 2;
        if (q == 1) sidx[t]       = point_index(v.x, v.y);
        if (q == 2) sidx[TOK + t] = point_index(v.x, v.y);
    }
    __syncthreads();   // the only barrier

    // ---- direct store: flat l -> (t = l/68, j = l%68) float4 of the row.
    // All row-segment boundaries (floats 6,134,138,266) are even, so each
    // 16B output vec4 is two float2 halves, each from exactly one source.
    // Half h (float2 units, 0..135):
    //   h<3: x[2h..]  h<67: e1[2h-6..]  h<69: x[2h-128..]
    //   h<133: e2[2h-138..]  else x[2h-256..]
    const float2* xs2 = (const float2*)xs;
    const float2* se2 = (const float2*)semb;
    const long long out4 = (long long)tok0 * 68;

    // exact for l < ~1M: floor(l*61681 / 2^22) == floor(l/68)
#define BODY(lv)                                                           \
    {                                                                      \
        const int l_ = (lv);                                               \
        int t  = (int)(((unsigned)l_ * 61681u) >> 22);                     \
        int j  = l_ - t * 68;                                              \
        int i1 = sidx[t];                                                  \
        int i2 = sidx[TOK + t];                                            \
        int tb = t * 8;                                                    \
        int h0 = 2 * j;                                                    \
        const float2* p0 = (h0 < 3)   ? xs2 + tb + h0                      \
                         : (h0 < 67)  ? se2 + i1 * 64 + (h0 - 3)           \
                         : (h0 < 69)  ? xs2 + tb + (h0 - 64)               \
                         : (h0 < 133) ? se2 + i2 * 64 + (h0 - 69)          \
                         :              xs2 + tb + (h0 - 128);             \
        int h1 = h0 + 1;                                                   \
        const float2* p1 = (h1 < 3)   ? xs2 + tb + h1                      \
                         : (h1 < 67)  ? se2 + i1 * 64 + (h1 - 3)           \
                         : (h1 < 69)  ? xs2 + tb + (h1 - 64)               \
                         : (h1 < 133) ? se2 + i2 * 64 + (h1 - 69)          \
                         :              xs2 + tb + (h1 - 128);             \
        float2 a = *p0, b = *p1;                                           \
        vfloat4 v; v.x = a.x; v.y = a.y; v.z = b.x; v.w = b.y;             \
        __builtin_nontemporal_store(v, &((vfloat4*)out)[out4 + l_]);       \
    }

    if (ntok == TOK) {
        // full block: every thread does exactly 17 vec4 (64*68/256)
#pragma unroll 4
        for (int k = 0; k < 17; ++k) BODY(tid + (k << 8));
    } else {
        const int nvec = ntok * 68;
        for (int l = tid; l < nvec; l += THREADS) BODY(l);
    }
#undef BODY
}

extern "C" void kernel_launch(void* const* d_in, const int* in_sizes, int n_in,
                              void* d_out, int out_size, void* d_ws, size_t ws_size,
                              hipStream_t stream) {
    const float* x   = (const float*)d_in[0];   // [B, T, 16] f32
    const float* emb = (const float*)d_in[1];   // [100, 128] f32
    float* out = (float*)d_out;                 // [B, T, 272] f32

    int n_tokens = in_sizes[0] / 16;            // 262144
    int nblocks  = (n_tokens + TOK - 1) / TOK;  // 4096

    pos_enc_kernel<<<nblocks, THREADS, 0, stream>>>(x, emb, out, n_tokens);
}